// Round 3
// baseline (673.818 us; speedup 1.0000x reference)
//
#include <hip/hip_runtime.h>

#define T_    1024
#define H_    2048
#define NH_   16
#define NKV_  4
#define HD_   128
#define E_    16
#define I_    768
#define QKVN  3072

typedef __attribute__((ext_vector_type(8))) short  short8;
typedef __attribute__((ext_vector_type(4))) float  f32x4;
typedef unsigned short u16;

__device__ inline u16 f2bf(float f) {
  unsigned u = __builtin_bit_cast(unsigned, f);
  return (u16)((u + 0x7fffu + ((u >> 16) & 1u)) >> 16);
}
__device__ inline float bf2f(u16 h) {
  unsigned u = ((unsigned)h) << 16;
  return __builtin_bit_cast(float, u);
}

__device__ inline float blk_sum(float v, float* lds) {
#pragma unroll
  for (int o = 32; o; o >>= 1) v += __shfl_down(v, o);
  int w = threadIdx.x >> 6;
  __syncthreads();
  if ((threadIdx.x & 63) == 0) lds[w] = v;
  __syncthreads();
  float s = lds[0];
  int nw = blockDim.x >> 6;
  for (int i = 1; i < nw; ++i) s += lds[i];
  return s;
}
__device__ inline float blk_max(float v, float* lds) {
#pragma unroll
  for (int o = 32; o; o >>= 1) v = fmaxf(v, __shfl_down(v, o));
  int w = threadIdx.x >> 6;
  __syncthreads();
  if ((threadIdx.x & 63) == 0) lds[w] = v;
  __syncthreads();
  float s = lds[0];
  int nw = blockDim.x >> 6;
  for (int i = 1; i < nw; ++i) s = fmaxf(s, lds[i]);
  return s;
}

// ---------- transpose + fp32->bf16 convert: in [R][C] f32 -> out [C][R] bf16 ----------
__global__ __launch_bounds__(256) void k_convT(const float* __restrict__ in,
                                               u16* __restrict__ out, int R, int C) {
  __shared__ u16 tile[64][66];
  const float* src = in + (size_t)blockIdx.z * R * C;
  u16* dst = out + (size_t)blockIdx.z * R * C;
  int c0 = blockIdx.x * 64, r0 = blockIdx.y * 64;
  int tid = threadIdx.x;
#pragma unroll
  for (int p = 0; p < 4; ++p) {
    int u = tid + 256 * p;
    int r = u >> 4, c4 = (u & 15) * 4;
    float4 v = *(const float4*)(src + (size_t)(r0 + r) * C + c0 + c4);
    tile[r][c4 + 0] = f2bf(v.x);
    tile[r][c4 + 1] = f2bf(v.y);
    tile[r][c4 + 2] = f2bf(v.z);
    tile[r][c4 + 3] = f2bf(v.w);
  }
  __syncthreads();
#pragma unroll
  for (int p = 0; p < 2; ++p) {
    int u = tid + 256 * p;
    int c = u >> 3, rg = (u & 7) * 8;
    unsigned x0 = tile[rg + 0][c] | ((unsigned)tile[rg + 1][c] << 16);
    unsigned x1 = tile[rg + 2][c] | ((unsigned)tile[rg + 3][c] << 16);
    unsigned x2 = tile[rg + 4][c] | ((unsigned)tile[rg + 5][c] << 16);
    unsigned x3 = tile[rg + 6][c] | ((unsigned)tile[rg + 7][c] << 16);
    *(uint4*)(dst + (size_t)(c0 + c) * R + r0 + rg) = make_uint4(x0, x1, x2, x3);
  }
}

// ---------------- GEMM primitives ----------------
// All operands bf16, rows along K contiguous. Tile BM x 128 x BK, 4 waves (2x2),
// wave tile (BM/2) x 64, MR = BM/32 fragment rows.

template<int ROWS, int BK, bool GATHER>
__device__ inline void ldT(uint4* r, const u16* A, int stride, int row0, int k0,
                           const int* gat) {
  constexpr int RS = BK / 8;                 // uint4 chunks per row
  constexpr int CH = ROWS * BK / 2048;       // chunks per thread
#pragma unroll
  for (int i = 0; i < CH; ++i) {
    int u = threadIdx.x + 256 * i;
    int row = u / RS, kg = (u % RS) * 8;
    int grow = GATHER ? gat[row] : (row0 + row);
    r[i] = *(const uint4*)(A + (size_t)grow * stride + k0 + kg);
  }
}
template<int ROWS, int BK>
__device__ inline void wrT(u16* lds, const uint4* r) {
  constexpr int RS = BK / 8;
  constexpr int CH = ROWS * BK / 2048;
  constexpr int LDP = BK + 8;
#pragma unroll
  for (int i = 0; i < CH; ++i) {
    int u = threadIdx.x + 256 * i;
    int row = u / RS, kg = (u % RS) * 8;
    *(uint4*)(lds + row * LDP + kg) = r[i];
  }
}
template<int MR, int BK>
__device__ inline void mmaT(const u16* As, const u16* Bs, f32x4 acc[][4]) {
  constexpr int LDP = BK + 8;
  const int lane = threadIdx.x & 63, wv = threadIdx.x >> 6;
  const int wr = wv >> 1, wc = wv & 1;
  const int kk = (lane >> 4) * 8, rr = lane & 15;
#pragma unroll
  for (int kh = 0; kh < BK / 32; ++kh) {
    short8 aF[MR], bF[4];
#pragma unroll
    for (int m = 0; m < MR; ++m)
      aF[m] = *(const short8*)(As + (wr * MR * 16 + m * 16 + rr) * LDP + kh * 32 + kk);
#pragma unroll
    for (int n = 0; n < 4; ++n)
      bF[n] = *(const short8*)(Bs + (wc * 64 + n * 16 + rr) * LDP + kh * 32 + kk);
#pragma unroll
    for (int m = 0; m < MR; ++m)
#pragma unroll
      for (int n = 0; n < 4; ++n)
        acc[m][n] = __builtin_amdgcn_mfma_f32_16x16x32_bf16(aF[m], bF[n], acc[m][n], 0, 0, 0);
  }
}

#define ZERO_ACC(acc, MR) do { \
  _Pragma("unroll") for (int m_ = 0; m_ < MR; ++m_) \
  _Pragma("unroll") for (int n_ = 0; n_ < 4; ++n_) acc[m_][n_] = (f32x4){0.f,0.f,0.f,0.f}; \
} while (0)

#define EPI_ROW(MR, m, r)  (((threadIdx.x >> 6) >> 1) * (MR*16) + (m)*16 + (((threadIdx.x&63) >> 4) * 4) + (r))
#define EPI_COL(n)         ((((threadIdx.x >> 6) & 1) * 64) + (n)*16 + ((threadIdx.x&63) & 15))

// Double-buffered LDS + 2-deep register prefetch pipeline. NT must be even >= 2.
template<int BM, int BK, int NT, bool GATHER>
__device__ inline void gemm_pipe(const u16* Ab, int sA, int rowA, const int* gat,
                                 const u16* Bb, int sB, int rowB,
                                 u16* A0, u16* B0, u16* A1, u16* B1,
                                 f32x4 acc[][4]) {
  constexpr int AU = BM * BK / 2048, BU = 128 * BK / 2048, MR = BM / 32;
  uint4 a0[AU], b0[BU], a1[AU], b1[BU];
  ldT<BM, BK, GATHER>(a0, Ab, sA, rowA, 0, gat);
  ldT<128, BK, false>(b0, Bb, sB, rowB, 0, nullptr);
  ldT<BM, BK, GATHER>(a1, Ab, sA, rowA, BK, gat);
  ldT<128, BK, false>(b1, Bb, sB, rowB, BK, nullptr);
  wrT<BM, BK>(A0, a0); wrT<128, BK>(B0, b0);
  if (NT > 2) {
    ldT<BM, BK, GATHER>(a0, Ab, sA, rowA, 2 * BK, gat);
    ldT<128, BK, false>(b0, Bb, sB, rowB, 2 * BK, nullptr);
  }
#pragma unroll 1
  for (int kt = 0; kt < NT; kt += 2) {
    __syncthreads();
    wrT<BM, BK>(A1, a1); wrT<128, BK>(B1, b1);
    if (kt + 3 < NT) {
      ldT<BM, BK, GATHER>(a1, Ab, sA, rowA, (kt + 3) * BK, gat);
      ldT<128, BK, false>(b1, Bb, sB, rowB, (kt + 3) * BK, nullptr);
    }
    mmaT<MR, BK>(A0, B0, acc);
    __syncthreads();
    if (kt + 2 < NT) { wrT<BM, BK>(A0, a0); wrT<128, BK>(B0, b0); }
    if (kt + 4 < NT) {
      ldT<BM, BK, GATHER>(a0, Ab, sA, rowA, (kt + 4) * BK, gat);
      ldT<128, BK, false>(b0, Bb, sB, rowB, (kt + 4) * BK, nullptr);
    }
    mmaT<MR, BK>(A1, B1, acc);
  }
}

// ---------------- kernels ----------------

__global__ __launch_bounds__(256) void k_rms1(const float* x, const float* w, u16* out) {
  __shared__ float lds[4];
  int t = blockIdx.x, tid = threadIdx.x;
  float v[8]; float ss = 0.f;
#pragma unroll
  for (int i = 0; i < 8; ++i) { v[i] = x[(size_t)t * H_ + tid + 256 * i]; ss += v[i] * v[i]; }
  ss = blk_sum(ss, lds);
  float inv = rsqrtf(ss * (1.f / H_) + 1e-6f);
#pragma unroll
  for (int i = 0; i < 8; ++i)
    out[(size_t)t * H_ + tid + 256 * i] = f2bf(v[i] * inv * w[tid + 256 * i]);
}

__global__ __launch_bounds__(256) void k_rms2(const float* x, const float* w,
                                              float* outf, u16* outb) {
  __shared__ float lds[4];
  int t = blockIdx.x, tid = threadIdx.x;
  float v[8]; float ss = 0.f;
#pragma unroll
  for (int i = 0; i < 8; ++i) { v[i] = x[(size_t)t * H_ + tid + 256 * i]; ss += v[i] * v[i]; }
  ss = blk_sum(ss, lds);
  float inv = rsqrtf(ss * (1.f / H_) + 1e-6f);
#pragma unroll
  for (int i = 0; i < 8; ++i) {
    float r = v[i] * inv * w[tid + 256 * i];
    outf[(size_t)t * H_ + tid + 256 * i] = r;
    outb[(size_t)t * H_ + tid + 256 * i] = f2bf(r);
  }
}

// qkv: [1024 x 3072 x 2048], BM=128. grid (bn=24, bm=8)
__global__ __launch_bounds__(256) void k_qkv(const u16* h1, const u16* wqkvT, float* qkv) {
  __shared__ __align__(16) u16 A0[128 * 72], B0[128 * 72], A1[128 * 72], B1[128 * 72];
  int bn = blockIdx.x, bm = blockIdx.y;
  f32x4 acc[4][4]; ZERO_ACC(acc, 4);
  gemm_pipe<128, 64, H_ / 64, false>(h1, H_, bm * 128, nullptr,
                                     wqkvT, H_, bn * 128, A0, B0, A1, B1, acc);
#pragma unroll
  for (int m = 0; m < 4; ++m)
#pragma unroll
    for (int n = 0; n < 4; ++n) {
      f32x4 a = acc[m][n];
#pragma unroll
      for (int r = 0; r < 4; ++r)
        qkv[(size_t)(bm * 128 + EPI_ROW(4, m, r)) * QKVN + bn * 128 + EPI_COL(n)] = a[r];
    }
}

__global__ __launch_bounds__(256) void k_qkrope(const float* qkv, const int* pos,
                                                const float* wq, const float* wk,
                                                u16* q, u16* kk, u16* vT) {
  __shared__ float cs[64], sn[64];
  int t = blockIdx.x, tid = threadIdx.x, lane = tid & 63, w = tid >> 6;
  if (tid < 64) {
    float fr = expf(-((float)tid / 64.f) * 9.210340371976184f);
    float ang = (float)pos[t] * fr;
    float s_, c_; sincosf(ang, &s_, &c_);
    cs[tid] = c_; sn[tid] = s_;
  }
  __syncthreads();
  const float* row = qkv + (size_t)t * QKVN;
  for (int h = w; h < NH_; h += 4) {
    float x1 = row[h * 128 + lane], x2 = row[h * 128 + 64 + lane];
    float ss = x1 * x1 + x2 * x2;
#pragma unroll
    for (int o = 32; o; o >>= 1) ss += __shfl_down(ss, o);
    ss = __shfl(ss, 0);
    float inv = rsqrtf(ss * (1.f / HD_) + 1e-6f);
    float n1 = x1 * inv * wq[lane], n2 = x2 * inv * wq[64 + lane];
    float o1 = n1 * cs[lane] - n2 * sn[lane];
    float o2 = n2 * cs[lane] + n1 * sn[lane];
    q[(size_t)t * (NH_ * HD_) + h * 128 + lane] = f2bf(o1);
    q[(size_t)t * (NH_ * HD_) + h * 128 + 64 + lane] = f2bf(o2);
  }
  if (w < NKV_) {
    int h = w;
    float x1 = row[2048 + h * 128 + lane], x2 = row[2048 + h * 128 + 64 + lane];
    float ss = x1 * x1 + x2 * x2;
#pragma unroll
    for (int o = 32; o; o >>= 1) ss += __shfl_down(ss, o);
    ss = __shfl(ss, 0);
    float inv = rsqrtf(ss * (1.f / HD_) + 1e-6f);
    float n1 = x1 * inv * wk[lane], n2 = x2 * inv * wk[64 + lane];
    float o1 = n1 * cs[lane] - n2 * sn[lane];
    float o2 = n2 * cs[lane] + n1 * sn[lane];
    kk[((size_t)h * T_ + t) * HD_ + lane] = f2bf(o1);
    kk[((size_t)h * T_ + t) * HD_ + 64 + lane] = f2bf(o2);
    float v1 = row[2560 + h * 128 + lane], v2 = row[2560 + h * 128 + 64 + lane];
    vT[((size_t)(h * 128 + lane)) * T_ + t] = f2bf(v1);
    vT[((size_t)(h * 128 + 64 + lane)) * T_ + t] = f2bf(v2);
  }
}

// scores: per head [1024 x 1024 x 128], BM=64. grid (h=16, sn=8, qm=16)
__global__ __launch_bounds__(256) void k_scores(const u16* q, const u16* kb, u16* S) {
  __shared__ __align__(16) u16 A0[64 * 72], B0[128 * 72], A1[64 * 72], B1[128 * 72];
  int h = blockIdx.x, sn = blockIdx.y, qm = blockIdx.z;
  f32x4 acc[2][4]; ZERO_ACC(acc, 2);
  gemm_pipe<64, 64, HD_ / 64, false>(q + h * 128, NH_ * HD_, qm * 64, nullptr,
                                     kb + (size_t)(h >> 2) * T_ * HD_, HD_, sn * 128,
                                     A0, B0, A1, B1, acc);
  const float scale = 0.08838834764831845f;
#pragma unroll
  for (int m = 0; m < 2; ++m)
#pragma unroll
    for (int n = 0; n < 4; ++n) {
      f32x4 a = acc[m][n];
#pragma unroll
      for (int r = 0; r < 4; ++r)
        S[((size_t)h * T_ + qm * 64 + EPI_ROW(2, m, r)) * T_ + sn * 128 + EPI_COL(n)] =
            f2bf(a[r] * scale);
    }
}

__global__ __launch_bounds__(256) void k_softmax(u16* S) {
  __shared__ float lds[4];
  int t = blockIdx.x, h = blockIdx.y, tid = threadIdx.x;
  u16* rowp = S + ((size_t)h * T_ + t) * T_;
  float x[4];
#pragma unroll
  for (int i = 0; i < 4; ++i) x[i] = bf2f(rowp[tid + 256 * i]);
  float m = fmaxf(fmaxf(x[0], x[1]), fmaxf(x[2], x[3]));
  m = blk_max(m, lds);
  float s = 0.f;
#pragma unroll
  for (int i = 0; i < 4; ++i) { x[i] = __expf(x[i] - m); s += x[i]; }
  s = blk_sum(s, lds);
  float inv = 1.f / s;
#pragma unroll
  for (int i = 0; i < 4; ++i) rowp[tid + 256 * i] = f2bf(x[i] * inv);
}

// pv: per head [1024 x 128 x 1024], BM=64. grid (h=16, qm=16)
__global__ __launch_bounds__(256) void k_pv(const u16* P, const u16* vT, u16* ctx) {
  __shared__ __align__(16) u16 A0[64 * 72], B0[128 * 72], A1[64 * 72], B1[128 * 72];
  int h = blockIdx.x, qm = blockIdx.y;
  f32x4 acc[2][4]; ZERO_ACC(acc, 2);
  gemm_pipe<64, 64, T_ / 64, false>(P + (size_t)h * T_ * T_, T_, qm * 64, nullptr,
                                    vT + (size_t)(h >> 2) * HD_ * T_, T_, 0,
                                    A0, B0, A1, B1, acc);
#pragma unroll
  for (int m = 0; m < 2; ++m)
#pragma unroll
    for (int n = 0; n < 4; ++n) {
      f32x4 a = acc[m][n];
#pragma unroll
      for (int r = 0; r < 4; ++r)
        ctx[(size_t)(qm * 64 + EPI_ROW(2, m, r)) * (NH_ * HD_) + h * 128 + EPI_COL(n)] =
            f2bf(a[r]);
    }
}

// wo: [1024 x 2048 x 2048], BM=128. grid (bn=16, bm=8)
__global__ __launch_bounds__(256) void k_wo(const u16* ctx, const u16* woT,
                                            const float* hs, float* resid) {
  __shared__ __align__(16) u16 A0[128 * 72], B0[128 * 72], A1[128 * 72], B1[128 * 72];
  int bn = blockIdx.x, bm = blockIdx.y;
  f32x4 acc[4][4]; ZERO_ACC(acc, 4);
  gemm_pipe<128, 64, H_ / 64, false>(ctx, H_, bm * 128, nullptr,
                                     woT, H_, bn * 128, A0, B0, A1, B1, acc);
#pragma unroll
  for (int m = 0; m < 4; ++m)
#pragma unroll
    for (int n = 0; n < 4; ++n) {
      f32x4 a = acc[m][n];
#pragma unroll
      for (int r = 0; r < 4; ++r) {
        size_t idx = (size_t)(bm * 128 + EPI_ROW(4, m, r)) * H_ + bn * 128 + EPI_COL(n);
        resid[idx] = a[r] + hs[idx];
      }
    }
}

__global__ __launch_bounds__(256) void k_router(const float* h2f, const float* wr_,
                                                int* topi, float* topw, int* cnt) {
  __shared__ float xs[H_];
  __shared__ float red[4][16];
  __shared__ float lg[16];
  int t = blockIdx.x, tid = threadIdx.x;
#pragma unroll
  for (int i = 0; i < 8; ++i) xs[tid + 256 * i] = h2f[(size_t)t * H_ + tid + 256 * i];
  __syncthreads();
  int e = tid & 15, p = tid >> 4;
  float s = 0.f;
  int b0 = p * 128;
  for (int i = 0; i < 128; ++i) s += xs[b0 + i] * wr_[(size_t)(b0 + i) * E_ + e];
  s += __shfl_down(s, 32);
  s += __shfl_down(s, 16);
  int lane = tid & 63, w = tid >> 6;
  if (lane < 16) red[w][lane] = s;
  __syncthreads();
  if (tid < 16) lg[tid] = red[0][tid] + red[1][tid] + red[2][tid] + red[3][tid];
  __syncthreads();
  if (tid == 0) {
    float l1 = -1e30f; int e1 = 0;
    for (int i = 0; i < E_; ++i) if (lg[i] > l1) { l1 = lg[i]; e1 = i; }
    float l2 = -1e30f; int e2 = 0;
    for (int i = 0; i < E_; ++i) if (i != e1 && lg[i] > l2) { l2 = lg[i]; e2 = i; }
    float d = __expf(l2 - l1);
    float w1 = 1.f / (1.f + d), w2 = d / (1.f + d);
    topi[2 * t] = e1; topi[2 * t + 1] = e2;
    topw[2 * t] = w1; topw[2 * t + 1] = w2;
    atomicAdd(&cnt[e1], 1);
    atomicAdd(&cnt[e2], 1);
  }
}

__global__ void k_scan(const int* cnt, int* basearr) {
  if (threadIdx.x == 0) {
    int b = 0;
    for (int e = 0; e < E_; ++e) { basearr[e] = b; b += cnt[e]; }
    basearr[E_] = b;
  }
}

__global__ __launch_bounds__(256) void k_assign(const int* topi, const float* topw,
                                                const int* basearr, int* posc,
                                                int* tok, float* wslot) {
  int t = blockIdx.x * 256 + threadIdx.x;
  if (t < T_) {
#pragma unroll
    for (int j = 0; j < 2; ++j) {
      int e = topi[2 * t + j];
      int p = atomicAdd(&posc[e], 1);
      int s = basearr[e] + p;
      tok[s] = t;
      wslot[s] = topw[2 * t + j];
    }
  }
}

// gateup: BM=64, BK=32, dual-B. grid (e=16, bn=6, mt=16)
__global__ __launch_bounds__(256) void k_gateup(const u16* h2b,
                                                const u16* wgT, const u16* wuT,
                                                const int* cnt, const int* basearr, const int* tok,
                                                u16* act) {
  __shared__ __align__(16) u16 As0[64 * 40], Bg0[128 * 40], Bu0[128 * 40];
  __shared__ __align__(16) u16 As1[64 * 40], Bg1[128 * 40], Bu1[128 * 40];
  __shared__ int gat_s[64];
  int e = blockIdx.x;
  int c = cnt[e];
  int mt = blockIdx.z;
  if (mt * 64 >= c) return;
  int basee = basearr[e];
  int gmax = c - mt * 64;
  int n0 = blockIdx.y * 128;
  int tid = threadIdx.x;
  if (tid < 64) {
    int r = mt * 64 + tid;
    gat_s[tid] = (r < c) ? tok[basee + r] : tok[basee];
  }
  __syncthreads();
  const u16* Bg = wgT + (size_t)e * H_ * I_;   // [I][H]
  const u16* Bu = wuT + (size_t)e * H_ * I_;
  f32x4 accg[2][4], accu[2][4]; ZERO_ACC(accg, 2); ZERO_ACC(accu, 2);
  uint4 a0[1], a1[1], bg0[2], bg1[2], bu0[2], bu1[2];
  const int NT = H_ / 32;
  ldT<64, 32, true>(a0, h2b, H_, 0, 0, gat_s);
  ldT<128, 32, false>(bg0, Bg, H_, n0, 0, nullptr);
  ldT<128, 32, false>(bu0, Bu, H_, n0, 0, nullptr);
  ldT<64, 32, true>(a1, h2b, H_, 0, 32, gat_s);
  ldT<128, 32, false>(bg1, Bg, H_, n0, 32, nullptr);
  ldT<128, 32, false>(bu1, Bu, H_, n0, 32, nullptr);
  wrT<64, 32>(As0, a0); wrT<128, 32>(Bg0, bg0); wrT<128, 32>(Bu0, bu0);
  ldT<64, 32, true>(a0, h2b, H_, 0, 64, gat_s);
  ldT<128, 32, false>(bg0, Bg, H_, n0, 64, nullptr);
  ldT<128, 32, false>(bu0, Bu, H_, n0, 64, nullptr);
#pragma unroll 1
  for (int kt = 0; kt < NT; kt += 2) {
    __syncthreads();
    wrT<64, 32>(As1, a1); wrT<128, 32>(Bg1, bg1); wrT<128, 32>(Bu1, bu1);
    if (kt + 3 < NT) {
      ldT<64, 32, true>(a1, h2b, H_, 0, (kt + 3) * 32, gat_s);
      ldT<128, 32, false>(bg1, Bg, H_, n0, (kt + 3) * 32, nullptr);
      ldT<128, 32, false>(bu1, Bu, H_, n0, (kt + 3) * 32, nullptr);
    }
    mmaT<2, 32>(As0, Bg0, accg);
    mmaT<2, 32>(As0, Bu0, accu);
    __syncthreads();
    if (kt + 2 < NT) { wrT<64, 32>(As0, a0); wrT<128, 32>(Bg0, bg0); wrT<128, 32>(Bu0, bu0); }
    if (kt + 4 < NT) {
      ldT<64, 32, true>(a0, h2b, H_, 0, (kt + 4) * 32, gat_s);
      ldT<128, 32, false>(bg0, Bg, H_, n0, (kt + 4) * 32, nullptr);
      ldT<128, 32, false>(bu0, Bu, H_, n0, (kt + 4) * 32, nullptr);
    }
    mmaT<2, 32>(As1, Bg1, accg);
    mmaT<2, 32>(As1, Bu1, accu);
  }
  int slot0 = basee + mt * 64;
#pragma unroll
  for (int m = 0; m < 2; ++m)
#pragma unroll
    for (int n = 0; n < 4; ++n) {
      f32x4 g4 = accg[m][n], u4 = accu[m][n];
#pragma unroll
      for (int r = 0; r < 4; ++r) {
        int row = EPI_ROW(2, m, r);
        if (row >= gmax) continue;
        int col = EPI_COL(n);
        float g = g4[r], u = u4[r];
        float sg = g / (1.f + __expf(-g));
        act[(size_t)(slot0 + row) * I_ + n0 + col] = f2bf(sg * u);
      }
    }
}

// down: BM=64. grid (bn=16, mt=16, e=16)
__global__ __launch_bounds__(256) void k_down(const u16* act, const u16* wdT,
                                              const int* cnt, const int* basearr,
                                              const int* tok, const float* wslot,
                                              float* moe) {
  __shared__ __align__(16) u16 A0[64 * 72], B0[128 * 72], A1[64 * 72], B1[128 * 72];
  int e = blockIdx.z;
  int c = cnt[e];
  int mt = blockIdx.y;
  if (mt * 64 >= c) return;
  int basee = basearr[e];
  int gmax = c - mt * 64;
  int slot0 = basee + mt * 64;
  int n0 = blockIdx.x * 128;
  f32x4 acc[2][4]; ZERO_ACC(acc, 2);
  gemm_pipe<64, 64, I_ / 64, false>(act + (size_t)slot0 * I_, I_, 0, nullptr,
                                    wdT + (size_t)e * H_ * I_, I_, n0,
                                    A0, B0, A1, B1, acc);
#pragma unroll
  for (int m = 0; m < 2; ++m)
#pragma unroll
    for (int n = 0; n < 4; ++n) {
      f32x4 a = acc[m][n];
#pragma unroll
      for (int r = 0; r < 4; ++r) {
        int row = EPI_ROW(2, m, r);
        if (row >= gmax) continue;
        int col = EPI_COL(n);
        int slot = slot0 + row;
        float wgt = wslot[slot];
        int tk = tok[slot];
        atomicAdd(&moe[(size_t)tk * H_ + n0 + col], a[r] * wgt);
      }
    }
}

extern "C" void kernel_launch(void* const* d_in, const int* in_sizes, int n_in,
                              void* d_out, int out_size, void* d_ws, size_t ws_size,
                              hipStream_t stream) {
  const float* hs    = (const float*)d_in[0];
  const int*   pos   = (const int*)d_in[1];
  const float* wn1   = (const float*)d_in[2];
  const float* wn2   = (const float*)d_in[3];
  const float* wqkv  = (const float*)d_in[4];
  const float* wqn   = (const float*)d_in[5];
  const float* wkn   = (const float*)d_in[6];
  const float* wo    = (const float*)d_in[7];
  const float* wrt   = (const float*)d_in[8];
  const float* wg    = (const float*)d_in[9];
  const float* wu    = (const float*)d_in[10];
  const float* wd    = (const float*)d_in[11];
  float* out = (float*)d_out;
  float* moe_out = out;                       // T*H fp32
  float* resid   = out + (size_t)T_ * H_;     // T*H fp32

  char* ws = (char*)d_ws;
  size_t off = 0;
  auto alloc = [&](size_t bytes) { size_t r = off; off = (off + bytes + 255) & ~(size_t)255; return r; };
  u16*   h1    = (u16*)  (ws + alloc((size_t)T_ * H_ * 2));
  float* qkv   = (float*)(ws + alloc((size_t)T_ * QKVN * 4));
  u16*   q     = (u16*)  (ws + alloc((size_t)T_ * NH_ * HD_ * 2));
  u16*   kb    = (u16*)  (ws + alloc((size_t)NKV_ * T_ * HD_ * 2));
  u16*   vT    = (u16*)  (ws + alloc((size_t)NKV_ * HD_ * T_ * 2));
  u16*   S     = (u16*)  (ws + alloc((size_t)NH_ * T_ * T_ * 2));
  u16*   ctx   = (u16*)  (ws + alloc((size_t)T_ * NH_ * HD_ * 2));
  float* h2f   = (float*)(ws + alloc((size_t)T_ * H_ * 4));
  u16*   h2b   = (u16*)  (ws + alloc((size_t)T_ * H_ * 2));
  u16*   act   = (u16*)  (ws + alloc((size_t)(2 * T_ + 256) * I_ * 2));
  int*   topi  = (int*)  (ws + alloc((size_t)T_ * 2 * 4));
  float* topw  = (float*)(ws + alloc((size_t)T_ * 2 * 4));
  int*   cnt   = (int*)  (ws + alloc(32 * 4));
  int*   posc  = cnt + 16;
  int*   base  = (int*)  (ws + alloc(32 * 4));
  int*   tok   = (int*)  (ws + alloc((size_t)(2 * T_ + 128) * 4));
  float* wsl   = (float*)(ws + alloc((size_t)(2 * T_ + 128) * 4));
  u16*   wqkvT = (u16*)  (ws + alloc((size_t)QKVN * H_ * 2));
  u16*   woT   = (u16*)  (ws + alloc((size_t)H_ * H_ * 2));
  u16*   wgT   = (u16*)  (ws + alloc((size_t)E_ * H_ * I_ * 2));
  u16*   wuT   = (u16*)  (ws + alloc((size_t)E_ * H_ * I_ * 2));
  u16*   wdT   = (u16*)  (ws + alloc((size_t)E_ * I_ * H_ * 2));
  (void)ws_size; (void)in_sizes; (void)n_in; (void)out_size;

  hipMemsetAsync(moe_out, 0, (size_t)T_ * H_ * 4, stream);
  hipMemsetAsync(cnt, 0, 32 * 4, stream);

  // weight conversions (fp32 [R][C] -> bf16 [C][R])
  k_convT<<<dim3(QKVN / 64, H_ / 64, 1), 256, 0, stream>>>(wqkv, wqkvT, H_, QKVN);
  k_convT<<<dim3(H_ / 64, H_ / 64, 1), 256, 0, stream>>>(wo, woT, H_, H_);
  k_convT<<<dim3(I_ / 64, H_ / 64, E_), 256, 0, stream>>>(wg, wgT, H_, I_);
  k_convT<<<dim3(I_ / 64, H_ / 64, E_), 256, 0, stream>>>(wu, wuT, H_, I_);
  k_convT<<<dim3(H_ / 64, I_ / 64, E_), 256, 0, stream>>>(wd, wdT, I_, H_);

  k_rms1<<<T_, 256, 0, stream>>>(hs, wn1, h1);
  k_qkv<<<dim3(QKVN / 128, T_ / 128), 256, 0, stream>>>(h1, wqkvT, qkv);
  k_qkrope<<<T_, 256, 0, stream>>>(qkv, pos, wqn, wkn, q, kb, vT);
  k_scores<<<dim3(NH_, T_ / 128, T_ / 64), 256, 0, stream>>>(q, kb, S);
  k_softmax<<<dim3(T_, NH_), 256, 0, stream>>>(S);
  k_pv<<<dim3(NH_, T_ / 64), 256, 0, stream>>>(S, vT, ctx);
  k_wo<<<dim3(H_ / 128, T_ / 128), 256, 0, stream>>>(ctx, woT, hs, resid);
  k_rms2<<<T_, 256, 0, stream>>>(resid, wn2, h2f, h2b);
  k_router<<<T_, 256, 0, stream>>>(h2f, wrt, topi, topw, cnt);
  k_scan<<<1, 64, 0, stream>>>(cnt, base);
  k_assign<<<4, 256, 0, stream>>>(topi, topw, base, posc, tok, wsl);
  k_gateup<<<dim3(E_, I_ / 128, T_ / 64), 256, 0, stream>>>(h2b, wgT, wuT, cnt, base, tok, act);
  k_down<<<dim3(H_ / 128, T_ / 64, E_), 256, 0, stream>>>(act, wdT, cnt, base, tok, wsl, moe_out);
}

// Round 4
// 353.087 us; speedup vs baseline: 1.9084x; 1.9084x over previous
//
#include <hip/hip_runtime.h>

#define T_    1024
#define H_    2048
#define NH_   16
#define NKV_  4
#define HD_   128
#define E_    16
#define I_    768
#define QKVN  3072

typedef __attribute__((ext_vector_type(8))) short  short8;
typedef __attribute__((ext_vector_type(4))) float  f32x4;
typedef unsigned short u16;

#define LDP 40   // padded LDS K-stride (bf16): 80B rows, worst 2-way banks (free per m136)

__device__ inline u16 f2bf(float f) {
  unsigned u = __builtin_bit_cast(unsigned, f);
  return (u16)((u + 0x7fffu + ((u >> 16) & 1u)) >> 16);
}
__device__ inline float bf2f(u16 h) {
  unsigned u = ((unsigned)h) << 16;
  return __builtin_bit_cast(float, u);
}

__device__ inline float blk_sum(float v, float* lds) {
#pragma unroll
  for (int o = 32; o; o >>= 1) v += __shfl_down(v, o);
  int w = threadIdx.x >> 6;
  __syncthreads();
  if ((threadIdx.x & 63) == 0) lds[w] = v;
  __syncthreads();
  float s = lds[0];
  int nw = blockDim.x >> 6;
  for (int i = 1; i < nw; ++i) s += lds[i];
  return s;
}
__device__ inline float blk_max(float v, float* lds) {
#pragma unroll
  for (int o = 32; o; o >>= 1) v = fmaxf(v, __shfl_down(v, o));
  int w = threadIdx.x >> 6;
  __syncthreads();
  if ((threadIdx.x & 63) == 0) lds[w] = v;
  __syncthreads();
  float s = lds[0];
  int nw = blockDim.x >> 6;
  for (int i = 1; i < nw; ++i) s = fmaxf(s, lds[i]);
  return s;
}

// ---------------- GEMM primitives (512 threads, 8 waves 2Mx4N) ----------------
// Tile 128x128xBK32. Wave tile 64x32: 4 m-frags x 2 n-frags of 16x16x32.

struct F8 { float v[8]; };

// A/bf16-B tile: 128 rows x 32 k, 1 uint4 per thread
__device__ inline void wrS(u16* lds, const uint4& r) {
  int row = threadIdx.x >> 2, kg = (threadIdx.x & 3) * 8;
  *(uint4*)(lds + row * LDP + kg) = r;
}
__device__ inline void wrS(u16* lds, const F8& r) {
  int n = threadIdx.x & 127, kh = (threadIdx.x >> 7) * 8;
  uint4 w;
  w.x = (unsigned)f2bf(r.v[0]) | ((unsigned)f2bf(r.v[1]) << 16);
  w.y = (unsigned)f2bf(r.v[2]) | ((unsigned)f2bf(r.v[3]) << 16);
  w.z = (unsigned)f2bf(r.v[4]) | ((unsigned)f2bf(r.v[5]) << 16);
  w.w = (unsigned)f2bf(r.v[6]) | ((unsigned)f2bf(r.v[7]) << 16);
  *(uint4*)(lds + n * LDP + kh) = w;
}

__device__ inline void mma8(const u16* As, const u16* Bs, f32x4 acc[4][2]) {
  const int lane = threadIdx.x & 63, wv = threadIdx.x >> 6;
  const int wr = wv >> 2, wc = wv & 3;
  const int kk = (lane >> 4) * 8, rr = lane & 15;
  short8 aF[4], bF[2];
#pragma unroll
  for (int m = 0; m < 4; ++m)
    aF[m] = *(const short8*)(As + (wr * 64 + m * 16 + rr) * LDP + kk);
#pragma unroll
  for (int n = 0; n < 2; ++n)
    bF[n] = *(const short8*)(Bs + (wc * 32 + n * 16 + rr) * LDP + kk);
#pragma unroll
  for (int m = 0; m < 4; ++m)
#pragma unroll
    for (int n = 0; n < 2; ++n)
      acc[m][n] = __builtin_amdgcn_mfma_f32_16x16x32_bf16(aF[m], bF[n], acc[m][n], 0, 0, 0);
}

#define ZERO_ACC(acc) do { \
  _Pragma("unroll") for (int m_ = 0; m_ < 4; ++m_) \
  _Pragma("unroll") for (int n_ = 0; n_ < 2; ++n_) acc[m_][n_] = (f32x4){0.f,0.f,0.f,0.f}; \
} while (0)

#define EPI_ROW(m, r)  (((threadIdx.x >> 6) >> 2) * 64 + (m)*16 + (((threadIdx.x&63) >> 4) * 4) + (r))
#define EPI_COL(n)     ((((threadIdx.x >> 6) & 3) * 32) + (n)*16 + ((threadIdx.x&63) & 15))

// Double-buffered LDS + 2-deep register prefetch. NT even, >= 4.
template<int NT, class BT, class LA, class LB>
__device__ inline void pipe(LA la, LB lb, u16* A0, u16* B0, u16* A1, u16* B1,
                            f32x4 acc[4][2]) {
  uint4 a0, a1; BT b0, b1;
  la(a0, 0); lb(b0, 0);
  la(a1, 1); lb(b1, 1);
  wrS(A0, a0); wrS(B0, b0);
  la(a0, 2); lb(b0, 2);
#pragma unroll 1
  for (int kt = 0; kt < NT; kt += 2) {
    __syncthreads();
    wrS(A1, a1); wrS(B1, b1);
    if (kt + 3 < NT) { la(a1, kt + 3); lb(b1, kt + 3); }
    mma8(A0, B0, acc);
    __syncthreads();
    if (kt + 2 < NT) { wrS(A0, a0); wrS(B0, b0); }
    if (kt + 4 < NT) { la(a0, kt + 4); lb(b0, kt + 4); }
    mma8(A1, B1, acc);
  }
}

// ---------------- kernels ----------------

__global__ __launch_bounds__(256) void k_rms1(const float* x, const float* w, u16* out) {
  __shared__ float lds[4];
  int t = blockIdx.x, tid = threadIdx.x;
  float v[8]; float ss = 0.f;
#pragma unroll
  for (int i = 0; i < 8; ++i) { v[i] = x[(size_t)t * H_ + tid + 256 * i]; ss += v[i] * v[i]; }
  ss = blk_sum(ss, lds);
  float inv = rsqrtf(ss * (1.f / H_) + 1e-6f);
#pragma unroll
  for (int i = 0; i < 8; ++i)
    out[(size_t)t * H_ + tid + 256 * i] = f2bf(v[i] * inv * w[tid + 256 * i]);
}

__global__ __launch_bounds__(256) void k_rms2(const float* x, const float* w,
                                              float* outf, u16* outb) {
  __shared__ float lds[4];
  int t = blockIdx.x, tid = threadIdx.x;
  float v[8]; float ss = 0.f;
#pragma unroll
  for (int i = 0; i < 8; ++i) { v[i] = x[(size_t)t * H_ + tid + 256 * i]; ss += v[i] * v[i]; }
  ss = blk_sum(ss, lds);
  float inv = rsqrtf(ss * (1.f / H_) + 1e-6f);
#pragma unroll
  for (int i = 0; i < 8; ++i) {
    float r = v[i] * inv * w[tid + 256 * i];
    outf[(size_t)t * H_ + tid + 256 * i] = r;
    outb[(size_t)t * H_ + tid + 256 * i] = f2bf(r);
  }
}

// qkv: [1024 x 3072 x 2048]. grid (24, 8)
__global__ __launch_bounds__(512) void k_qkv(const u16* h1, const float* wqkv, float* qkv) {
  __shared__ __align__(16) u16 A0[128 * LDP], B0[128 * LDP], A1[128 * LDP], B1[128 * LDP];
  int bn = blockIdx.x, bm = blockIdx.y;
  f32x4 acc[4][2]; ZERO_ACC(acc);
  auto la = [&](uint4& r, int kt) {
    int row = threadIdx.x >> 2, kg = (threadIdx.x & 3) * 8;
    r = *(const uint4*)(h1 + (size_t)(bm * 128 + row) * H_ + kt * 32 + kg);
  };
  auto lb = [&](F8& r, int kt) {
    int n = threadIdx.x & 127, kh = (threadIdx.x >> 7) * 8;
    const float* src = wqkv + (size_t)(kt * 32 + kh) * QKVN + bn * 128 + n;
#pragma unroll
    for (int j = 0; j < 8; ++j) r.v[j] = src[(size_t)j * QKVN];
  };
  pipe<H_ / 32, F8>(la, lb, A0, B0, A1, B1, acc);
#pragma unroll
  for (int m = 0; m < 4; ++m)
#pragma unroll
    for (int n = 0; n < 2; ++n) {
      f32x4 a = acc[m][n];
#pragma unroll
      for (int r = 0; r < 4; ++r)
        qkv[(size_t)(bm * 128 + EPI_ROW(m, r)) * QKVN + bn * 128 + EPI_COL(n)] = a[r];
    }
}

__global__ __launch_bounds__(256) void k_qkrope(const float* qkv, const int* pos,
                                                const float* wq, const float* wk,
                                                u16* q, u16* kk, u16* vT) {
  __shared__ float cs[64], sn[64];
  int t = blockIdx.x, tid = threadIdx.x, lane = tid & 63, w = tid >> 6;
  if (tid < 64) {
    float fr = expf(-((float)tid / 64.f) * 9.210340371976184f);
    float ang = (float)pos[t] * fr;
    float s_, c_; sincosf(ang, &s_, &c_);
    cs[tid] = c_; sn[tid] = s_;
  }
  __syncthreads();
  const float* row = qkv + (size_t)t * QKVN;
  for (int h = w; h < NH_; h += 4) {
    float x1 = row[h * 128 + lane], x2 = row[h * 128 + 64 + lane];
    float ss = x1 * x1 + x2 * x2;
#pragma unroll
    for (int o = 32; o; o >>= 1) ss += __shfl_down(ss, o);
    ss = __shfl(ss, 0);
    float inv = rsqrtf(ss * (1.f / HD_) + 1e-6f);
    float n1 = x1 * inv * wq[lane], n2 = x2 * inv * wq[64 + lane];
    float o1 = n1 * cs[lane] - n2 * sn[lane];
    float o2 = n2 * cs[lane] + n1 * sn[lane];
    q[(size_t)t * (NH_ * HD_) + h * 128 + lane] = f2bf(o1);
    q[(size_t)t * (NH_ * HD_) + h * 128 + 64 + lane] = f2bf(o2);
  }
  if (w < NKV_) {
    int h = w;
    float x1 = row[2048 + h * 128 + lane], x2 = row[2048 + h * 128 + 64 + lane];
    float ss = x1 * x1 + x2 * x2;
#pragma unroll
    for (int o = 32; o; o >>= 1) ss += __shfl_down(ss, o);
    ss = __shfl(ss, 0);
    float inv = rsqrtf(ss * (1.f / HD_) + 1e-6f);
    float n1 = x1 * inv * wk[lane], n2 = x2 * inv * wk[64 + lane];
    float o1 = n1 * cs[lane] - n2 * sn[lane];
    float o2 = n2 * cs[lane] + n1 * sn[lane];
    kk[((size_t)h * T_ + t) * HD_ + lane] = f2bf(o1);
    kk[((size_t)h * T_ + t) * HD_ + 64 + lane] = f2bf(o2);
    float v1 = row[2560 + h * 128 + lane], v2 = row[2560 + h * 128 + 64 + lane];
    vT[((size_t)(h * 128 + lane)) * T_ + t] = f2bf(v1);
    vT[((size_t)(h * 128 + 64 + lane)) * T_ + t] = f2bf(v2);
  }
}

// scores: per head [1024 x 1024 x 128]. grid (16, 8, 8)
__global__ __launch_bounds__(512) void k_scores(const u16* q, const u16* kb, u16* S) {
  __shared__ __align__(16) u16 A0[128 * LDP], B0[128 * LDP], A1[128 * LDP], B1[128 * LDP];
  int h = blockIdx.x, sn = blockIdx.y, qm = blockIdx.z;
  const u16* Aq = q + h * 128;
  const u16* Bk = kb + (size_t)(h >> 2) * T_ * HD_;
  f32x4 acc[4][2]; ZERO_ACC(acc);
  auto la = [&](uint4& r, int kt) {
    int row = threadIdx.x >> 2, kg = (threadIdx.x & 3) * 8;
    r = *(const uint4*)(Aq + (size_t)(qm * 128 + row) * (NH_ * HD_) + kt * 32 + kg);
  };
  auto lb = [&](uint4& r, int kt) {
    int row = threadIdx.x >> 2, kg = (threadIdx.x & 3) * 8;
    r = *(const uint4*)(Bk + (size_t)(sn * 128 + row) * HD_ + kt * 32 + kg);
  };
  pipe<HD_ / 32, uint4>(la, lb, A0, B0, A1, B1, acc);
  const float scale = 0.08838834764831845f;
#pragma unroll
  for (int m = 0; m < 4; ++m)
#pragma unroll
    for (int n = 0; n < 2; ++n) {
      f32x4 a = acc[m][n];
#pragma unroll
      for (int r = 0; r < 4; ++r)
        S[((size_t)h * T_ + qm * 128 + EPI_ROW(m, r)) * T_ + sn * 128 + EPI_COL(n)] =
            f2bf(a[r] * scale);
    }
}

__global__ __launch_bounds__(256) void k_softmax(u16* S) {
  __shared__ float lds[4];
  int t = blockIdx.x, h = blockIdx.y, tid = threadIdx.x;
  u16* rowp = S + ((size_t)h * T_ + t) * T_;
  float x[4];
#pragma unroll
  for (int i = 0; i < 4; ++i) x[i] = bf2f(rowp[tid + 256 * i]);
  float m = fmaxf(fmaxf(x[0], x[1]), fmaxf(x[2], x[3]));
  m = blk_max(m, lds);
  float s = 0.f;
#pragma unroll
  for (int i = 0; i < 4; ++i) { x[i] = __expf(x[i] - m); s += x[i]; }
  s = blk_sum(s, lds);
  float inv = 1.f / s;
#pragma unroll
  for (int i = 0; i < 4; ++i) rowp[tid + 256 * i] = f2bf(x[i] * inv);
}

// pv: per head [1024 x 128 x 1024]. grid (16, 8)
__global__ __launch_bounds__(512) void k_pv(const u16* P, const u16* vT, u16* ctx) {
  __shared__ __align__(16) u16 A0[128 * LDP], B0[128 * LDP], A1[128 * LDP], B1[128 * LDP];
  int h = blockIdx.x, qm = blockIdx.y;
  const u16* Ap = P + (size_t)h * T_ * T_;
  const u16* Bv = vT + (size_t)(h >> 2) * HD_ * T_;
  f32x4 acc[4][2]; ZERO_ACC(acc);
  auto la = [&](uint4& r, int kt) {
    int row = threadIdx.x >> 2, kg = (threadIdx.x & 3) * 8;
    r = *(const uint4*)(Ap + (size_t)(qm * 128 + row) * T_ + kt * 32 + kg);
  };
  auto lb = [&](uint4& r, int kt) {
    int row = threadIdx.x >> 2, kg = (threadIdx.x & 3) * 8;
    r = *(const uint4*)(Bv + (size_t)row * T_ + kt * 32 + kg);
  };
  pipe<T_ / 32, uint4>(la, lb, A0, B0, A1, B1, acc);
#pragma unroll
  for (int m = 0; m < 4; ++m)
#pragma unroll
    for (int n = 0; n < 2; ++n) {
      f32x4 a = acc[m][n];
#pragma unroll
      for (int r = 0; r < 4; ++r)
        ctx[(size_t)(qm * 128 + EPI_ROW(m, r)) * (NH_ * HD_) + h * 128 + EPI_COL(n)] =
            f2bf(a[r]);
    }
}

// wo: [1024 x 2048 x 2048]. grid (16, 8)
__global__ __launch_bounds__(512) void k_wo(const u16* ctx, const float* wo,
                                            const float* hs, float* resid) {
  __shared__ __align__(16) u16 A0[128 * LDP], B0[128 * LDP], A1[128 * LDP], B1[128 * LDP];
  int bn = blockIdx.x, bm = blockIdx.y;
  f32x4 acc[4][2]; ZERO_ACC(acc);
  auto la = [&](uint4& r, int kt) {
    int row = threadIdx.x >> 2, kg = (threadIdx.x & 3) * 8;
    r = *(const uint4*)(ctx + (size_t)(bm * 128 + row) * H_ + kt * 32 + kg);
  };
  auto lb = [&](F8& r, int kt) {
    int n = threadIdx.x & 127, kh = (threadIdx.x >> 7) * 8;
    const float* src = wo + (size_t)(kt * 32 + kh) * H_ + bn * 128 + n;
#pragma unroll
    for (int j = 0; j < 8; ++j) r.v[j] = src[(size_t)j * H_];
  };
  pipe<H_ / 32, F8>(la, lb, A0, B0, A1, B1, acc);
#pragma unroll
  for (int m = 0; m < 4; ++m)
#pragma unroll
    for (int n = 0; n < 2; ++n) {
      f32x4 a = acc[m][n];
#pragma unroll
      for (int r = 0; r < 4; ++r) {
        size_t idx = (size_t)(bm * 128 + EPI_ROW(m, r)) * H_ + bn * 128 + EPI_COL(n);
        resid[idx] = a[r] + hs[idx];
      }
    }
}

__global__ __launch_bounds__(256) void k_router(const float* h2f, const float* wr_,
                                                int* topi, float* topw, int* cnt) {
  __shared__ float xs[H_];
  __shared__ float red[4][16];
  __shared__ float lg[16];
  int t = blockIdx.x, tid = threadIdx.x;
#pragma unroll
  for (int i = 0; i < 8; ++i) xs[tid + 256 * i] = h2f[(size_t)t * H_ + tid + 256 * i];
  __syncthreads();
  int e = tid & 15, p = tid >> 4;
  float s = 0.f;
  int b0 = p * 128;
  for (int i = 0; i < 128; ++i) s += xs[b0 + i] * wr_[(size_t)(b0 + i) * E_ + e];
  s += __shfl_down(s, 32);
  s += __shfl_down(s, 16);
  int lane = tid & 63, w = tid >> 6;
  if (lane < 16) red[w][lane] = s;
  __syncthreads();
  if (tid < 16) lg[tid] = red[0][tid] + red[1][tid] + red[2][tid] + red[3][tid];
  __syncthreads();
  if (tid == 0) {
    float l1 = -1e30f; int e1 = 0;
    for (int i = 0; i < E_; ++i) if (lg[i] > l1) { l1 = lg[i]; e1 = i; }
    float l2 = -1e30f; int e2 = 0;
    for (int i = 0; i < E_; ++i) if (i != e1 && lg[i] > l2) { l2 = lg[i]; e2 = i; }
    float d = __expf(l2 - l1);
    float w1 = 1.f / (1.f + d), w2 = d / (1.f + d);
    topi[2 * t] = e1; topi[2 * t + 1] = e2;
    topw[2 * t] = w1; topw[2 * t + 1] = w2;
    atomicAdd(&cnt[e1], 1);
    atomicAdd(&cnt[e2], 1);
  }
}

__global__ void k_scan(const int* cnt, int* basearr) {
  if (threadIdx.x == 0) {
    int b = 0;
    for (int e = 0; e < E_; ++e) { basearr[e] = b; b += cnt[e]; }
    basearr[E_] = b;
  }
}

__global__ __launch_bounds__(256) void k_assign(const int* topi, const float* topw,
                                                const int* basearr, int* posc,
                                                int* tok, float* wslot) {
  int t = blockIdx.x * 256 + threadIdx.x;
  if (t < T_) {
#pragma unroll
    for (int j = 0; j < 2; ++j) {
      int e = topi[2 * t + j];
      int p = atomicAdd(&posc[e], 1);
      int s = basearr[e] + p;
      tok[s] = t;
      wslot[s] = topw[2 * t + j];
    }
  }
}

// gateup: BM=128 tokens, 64 output cols per block via interleaved [g|u] panel.
// grid (e=16, nb=12, mt=8). frag n=0 -> gate, n=1 -> up, same 16 cols.
__global__ __launch_bounds__(512) void k_gateup(const u16* h2b,
                                                const float* wg, const float* wu,
                                                const int* cnt, const int* basearr, const int* tok,
                                                u16* act) {
  __shared__ __align__(16) u16 A0[128 * LDP], B0[128 * LDP], A1[128 * LDP], B1[128 * LDP];
  __shared__ int gat_s[128];
  int e = blockIdx.x;
  int c = cnt[e];
  int mt = blockIdx.z;
  if (mt * 128 >= c) return;
  int basee = basearr[e];
  int gmax = c - mt * 128;
  int n0 = blockIdx.y * 64;
  int tid = threadIdx.x;
  if (tid < 128) {
    int r = mt * 128 + tid;
    gat_s[tid] = (r < c) ? tok[basee + r] : tok[basee];
  }
  __syncthreads();
  const float* Bg = wg + (size_t)e * H_ * I_;
  const float* Bu = wu + (size_t)e * H_ * I_;
  f32x4 acc[4][2]; ZERO_ACC(acc);
  auto la = [&](uint4& r, int kt) {
    int row = threadIdx.x >> 2, kg = (threadIdx.x & 3) * 8;
    r = *(const uint4*)(h2b + (size_t)gat_s[row] * H_ + kt * 32 + kg);
  };
  auto lb = [&](F8& r, int kt) {
    int cidx = threadIdx.x & 127, kh = (threadIdx.x >> 7) * 8;
    int fn = cidx >> 4;
    const float* base = (fn & 1) ? Bu : Bg;
    int col = n0 + (fn >> 1) * 16 + (cidx & 15);
    const float* src = base + (size_t)(kt * 32 + kh) * I_ + col;
#pragma unroll
    for (int j = 0; j < 8; ++j) r.v[j] = src[(size_t)j * I_];
  };
  pipe<H_ / 32, F8>(la, lb, A0, B0, A1, B1, acc);
  int slot0 = basee + mt * 128;
#pragma unroll
  for (int m = 0; m < 4; ++m) {
#pragma unroll
    for (int r = 0; r < 4; ++r) {
      int row = EPI_ROW(m, r);
      if (row >= gmax) continue;
      int col = n0 + ((threadIdx.x >> 6) & 3) * 16 + ((threadIdx.x & 63) & 15);
      float g = acc[m][0][r], u = acc[m][1][r];
      float sg = g / (1.f + __expf(-g));
      act[(size_t)(slot0 + row) * I_ + col] = f2bf(sg * u);
    }
  }
}

// down: BM=128. grid (bn=16, e=16, mt=8)
__global__ __launch_bounds__(512) void k_down(const u16* act, const float* wd,
                                              const int* cnt, const int* basearr,
                                              const int* tok, const float* wslot,
                                              float* moe) {
  __shared__ __align__(16) u16 A0[128 * LDP], B0[128 * LDP], A1[128 * LDP], B1[128 * LDP];
  int e = blockIdx.y;
  int c = cnt[e];
  int mt = blockIdx.z;
  if (mt * 128 >= c) return;
  int basee = basearr[e];
  int gmax = c - mt * 128;
  int slot0 = basee + mt * 128;
  int n0 = blockIdx.x * 128;
  const u16* Ap = act + (size_t)slot0 * I_;
  const float* Bp = wd + (size_t)e * I_ * H_;
  f32x4 acc[4][2]; ZERO_ACC(acc);
  auto la = [&](uint4& r, int kt) {
    int row = threadIdx.x >> 2, kg = (threadIdx.x & 3) * 8;
    r = *(const uint4*)(Ap + (size_t)row * I_ + kt * 32 + kg);
  };
  auto lb = [&](F8& r, int kt) {
    int n = threadIdx.x & 127, kh = (threadIdx.x >> 7) * 8;
    const float* src = Bp + (size_t)(kt * 32 + kh) * H_ + n0 + n;
#pragma unroll
    for (int j = 0; j < 8; ++j) r.v[j] = src[(size_t)j * H_];
  };
  pipe<I_ / 32, F8>(la, lb, A0, B0, A1, B1, acc);
#pragma unroll
  for (int m = 0; m < 4; ++m)
#pragma unroll
    for (int n = 0; n < 2; ++n) {
      f32x4 a = acc[m][n];
#pragma unroll
      for (int r = 0; r < 4; ++r) {
        int row = EPI_ROW(m, r);
        if (row >= gmax) continue;
        int col = EPI_COL(n);
        int slot = slot0 + row;
        float wgt = wslot[slot];
        int tk = tok[slot];
        atomicAdd(&moe[(size_t)tk * H_ + n0 + col], a[r] * wgt);
      }
    }
}

extern "C" void kernel_launch(void* const* d_in, const int* in_sizes, int n_in,
                              void* d_out, int out_size, void* d_ws, size_t ws_size,
                              hipStream_t stream) {
  const float* hs    = (const float*)d_in[0];
  const int*   pos   = (const int*)d_in[1];
  const float* wn1   = (const float*)d_in[2];
  const float* wn2   = (const float*)d_in[3];
  const float* wqkv  = (const float*)d_in[4];
  const float* wqn   = (const float*)d_in[5];
  const float* wkn   = (const float*)d_in[6];
  const float* wo    = (const float*)d_in[7];
  const float* wrt   = (const float*)d_in[8];
  const float* wg    = (const float*)d_in[9];
  const float* wu    = (const float*)d_in[10];
  const float* wd    = (const float*)d_in[11];
  float* out = (float*)d_out;
  float* moe_out = out;                       // T*H fp32
  float* resid   = out + (size_t)T_ * H_;     // T*H fp32

  char* ws = (char*)d_ws;
  size_t off = 0;
  auto alloc = [&](size_t bytes) { size_t r = off; off = (off + bytes + 255) & ~(size_t)255; return r; };
  u16*   h1   = (u16*)  (ws + alloc((size_t)T_ * H_ * 2));
  float* qkv  = (float*)(ws + alloc((size_t)T_ * QKVN * 4));
  u16*   q    = (u16*)  (ws + alloc((size_t)T_ * NH_ * HD_ * 2));
  u16*   kb   = (u16*)  (ws + alloc((size_t)NKV_ * T_ * HD_ * 2));
  u16*   vT   = (u16*)  (ws + alloc((size_t)NKV_ * HD_ * T_ * 2));
  u16*   S    = (u16*)  (ws + alloc((size_t)NH_ * T_ * T_ * 2));
  u16*   ctx  = (u16*)  (ws + alloc((size_t)T_ * NH_ * HD_ * 2));
  float* h2f  = (float*)(ws + alloc((size_t)T_ * H_ * 4));
  u16*   h2b  = (u16*)  (ws + alloc((size_t)T_ * H_ * 2));
  u16*   act  = (u16*)  (ws + alloc((size_t)(2 * T_ + 256) * I_ * 2));
  int*   topi = (int*)  (ws + alloc((size_t)T_ * 2 * 4));
  float* topw = (float*)(ws + alloc((size_t)T_ * 2 * 4));
  int*   cnt  = (int*)  (ws + alloc(32 * 4));
  int*   posc = cnt + 16;
  int*   base = (int*)  (ws + alloc(32 * 4));
  int*   tok  = (int*)  (ws + alloc((size_t)(2 * T_ + 128) * 4));
  float* wsl  = (float*)(ws + alloc((size_t)(2 * T_ + 128) * 4));
  (void)ws_size; (void)in_sizes; (void)n_in; (void)out_size;

  hipMemsetAsync(moe_out, 0, (size_t)T_ * H_ * 4, stream);
  hipMemsetAsync(cnt, 0, 32 * 4, stream);

  k_rms1<<<T_, 256, 0, stream>>>(hs, wn1, h1);
  k_qkv<<<dim3(QKVN / 128, T_ / 128), 512, 0, stream>>>(h1, wqkv, qkv);
  k_qkrope<<<T_, 256, 0, stream>>>(qkv, pos, wqn, wkn, q, kb, vT);
  k_scores<<<dim3(NH_, T_ / 128, T_ / 128), 512, 0, stream>>>(q, kb, S);
  k_softmax<<<dim3(T_, NH_), 256, 0, stream>>>(S);
  k_pv<<<dim3(NH_, T_ / 128), 512, 0, stream>>>(S, vT, ctx);
  k_wo<<<dim3(H_ / 128, T_ / 128), 512, 0, stream>>>(ctx, wo, hs, resid);
  k_rms2<<<T_, 256, 0, stream>>>(resid, wn2, h2f, h2b);
  k_router<<<T_, 256, 0, stream>>>(h2f, wrt, topi, topw, cnt);
  k_scan<<<1, 64, 0, stream>>>(cnt, base);
  k_assign<<<4, 256, 0, stream>>>(topi, topw, base, posc, tok, wsl);
  k_gateup<<<dim3(E_, I_ / 64, T_ / 128), 512, 0, stream>>>(h2b, wg, wu, cnt, base, tok, act);
  k_down<<<dim3(H_ / 128, E_, T_ / 128), 512, 0, stream>>>(act, wd, cnt, base, tok, wsl, moe_out);
}